// Round 3
// baseline (477.317 us; speedup 1.0000x reference)
//
#include <hip/hip_runtime.h>
#include <hip/hip_bf16.h>

#define DIM 128

typedef __attribute__((ext_vector_type(8))) short bf16x8;
typedef __attribute__((ext_vector_type(4))) float f32x4;

__device__ __forceinline__ float bfu_lo(unsigned u) { return __uint_as_float(u << 16); }
__device__ __forceinline__ float bfu_hi(unsigned u) { return __uint_as_float(u & 0xffff0000u); }
__device__ __forceinline__ unsigned short f2bf(float f) {
    unsigned u = __float_as_uint(f);
    u += 0x7fffu + ((u >> 16) & 1u);   // round-to-nearest-even
    return (unsigned short)(u >> 16);
}

// Deterministic edge-width sniff (same data every call -> graph-safe).
// flags[0]=1 iff edge_index is int64 (odd 32-bit words -- the high halves -- are all zero).
__global__ void detect(const unsigned* ei_w, int* flags) {
    __shared__ unsigned s_or[256];
    int t = threadIdx.x;
    unsigned o = 0;
    for (int i = t; i < 4096; i += 256) o |= ei_w[2 * i + 1];
    s_or[t] = o;
    __syncthreads();
    for (int s = 128; s > 0; s >>= 1) {
        if (t < s) s_or[t] |= s_or[t + s];
        __syncthreads();
    }
    if (t == 0) flags[0] = (s_or[0] == 0u) ? 1 : 0;
}

__device__ __forceinline__ int edge_at(const void* ei, int idx64, long long pos) {
    return idx64 ? (int)((const long long*)ei)[pos] : ((const int*)ei)[pos];
}

__global__ void zero_u32(unsigned* p, int n) {
    int i = blockIdx.x * 256 + threadIdx.x;
    if (i < n) p[i] = 0u;
}

// deg[d] = number of incoming edges at d (self-loop added later as +1)
__global__ void count_deg(const void* ei, unsigned* deg, const int* flags, int E) {
    int e = blockIdx.x * 256 + threadIdx.x;
    int idx64 = flags[0];
    if (e < E) {
        int d = edge_at(ei, idx64, (long long)E + e);
        atomicAdd(&deg[d], 1u);
    }
}

// per-block exclusive scan of deg -> row_start (partial), block totals -> blockSums
__global__ void scan1(const unsigned* deg, unsigned* row_start, unsigned* blockSums, int N) {
    __shared__ unsigned wsum[4];
    int t = threadIdx.x;
    int i = blockIdx.x * 256 + t;
    unsigned v = (i < N) ? deg[i] : 0u;
    unsigned s = v;
    int lane = t & 63;
#pragma unroll
    for (int off = 1; off < 64; off <<= 1) {
        unsigned u = __shfl_up(s, off, 64);
        if (lane >= off) s += u;
    }
    int w = t >> 6;
    if (lane == 63) wsum[w] = s;
    __syncthreads();
    unsigned woff = 0;
    for (int j = 0; j < w; j++) woff += wsum[j];
    unsigned excl = woff + s - v;
    if (i < N) row_start[i] = excl;
    if (t == 255) blockSums[blockIdx.x] = woff + s;
}

// single-block exclusive scan of blockSums (nb <= 512)
__global__ void scan2(unsigned* blockSums, int nb) {
    __shared__ unsigned wsum[8];
    int t = threadIdx.x;
    unsigned v = (t < nb) ? blockSums[t] : 0u;
    unsigned s = v;
    int lane = t & 63;
#pragma unroll
    for (int off = 1; off < 64; off <<= 1) {
        unsigned u = __shfl_up(s, off, 64);
        if (lane >= off) s += u;
    }
    int w = t >> 6;
    if (lane == 63) wsum[w] = s;
    __syncthreads();
    unsigned woff = 0;
    for (int j = 0; j < w; j++) woff += wsum[j];
    if (t < nb) blockSums[t] = woff + s - v;
}

__global__ void finalize_csr(const unsigned* deg, unsigned* row_start, unsigned* cursor,
                             float* dis, const unsigned* blockSums, int N) {
    int i = blockIdx.x * 256 + threadIdx.x;
    if (i < N) {
        unsigned rs = row_start[i] + blockSums[i >> 8];
        row_start[i] = rs;
        cursor[i] = rs;
        dis[i] = rsqrtf((float)deg[i] + 1.0f);  // +1 self-loop
    }
}

__global__ void fill_csr(const void* ei, unsigned* cursor, int* col_src, const int* flags, int E) {
    int e = blockIdx.x * 256 + threadIdx.x;
    int idx64 = flags[0];
    if (e < E) {
        int s = edge_at(ei, idx64, e);
        int d = edge_at(ei, idx64, (long long)E + e);
        unsigned pos = atomicAdd(&cursor[d], 1u);
        col_src[pos] = s;
    }
}

// Wt[n][k] = bf16(W[k][n]); W is fp32 [128][128]
__global__ void transposeW(const float* W, unsigned short* Wt) {
    int idx = blockIdx.x * 256 + threadIdx.x;   // 0..DIM*DIM-1
    if (idx < DIM * DIM) {
        int n = idx >> 7, k = idx & 127;
        Wt[idx] = f2bf(W[k * DIM + n]);
    }
}

// x_proj = x @ W, bf16 MFMA, x fp32 in / xproj packed-bf16 out.
// Block = 256 thr = 4 waves, 128 rows/block.
// Operand swap: mfma(Wfrag, Xfrag, acc) -> lane holds out[row=rowBase+l15][col=quad*4+reg]
__global__ __launch_bounds__(256) void gemm_xw(const float* __restrict__ x,
                                               const unsigned short* __restrict__ wt,
                                               unsigned short* __restrict__ xproj, int N) {
    int tid = threadIdx.x;
    int wv = tid >> 6, lane = tid & 63;
    int l15 = lane & 15, quad = lane >> 4;
    int rowBase = blockIdx.x * 128 + wv * 32;

    f32x4 acc[2][8];
#pragma unroll
    for (int mt = 0; mt < 2; mt++)
#pragma unroll
        for (int nt = 0; nt < 8; nt++)
            acc[mt][nt] = (f32x4){0.f, 0.f, 0.f, 0.f};

#pragma unroll
    for (int k0 = 0; k0 < DIM; k0 += 32) {
        bf16x8 aa[2], bb[8];
#pragma unroll
        for (int mt = 0; mt < 2; mt++) {
            int r = rowBase + mt * 16 + l15;
            if (r > N - 1) r = N - 1;           // clamp; garbage rows never stored
            const float* xf = x + (size_t)r * DIM + k0 + quad * 8;
            float4 u0 = ((const float4*)xf)[0];
            float4 u1 = ((const float4*)xf)[1];
            bf16x8 a;
            a[0] = (short)f2bf(u0.x); a[1] = (short)f2bf(u0.y);
            a[2] = (short)f2bf(u0.z); a[3] = (short)f2bf(u0.w);
            a[4] = (short)f2bf(u1.x); a[5] = (short)f2bf(u1.y);
            a[6] = (short)f2bf(u1.z); a[7] = (short)f2bf(u1.w);
            aa[mt] = a;
        }
#pragma unroll
        for (int nt = 0; nt < 8; nt++)
            bb[nt] = *(const bf16x8*)(wt + (size_t)(nt * 16 + l15) * DIM + k0 + quad * 8);
#pragma unroll
        for (int mt = 0; mt < 2; mt++)
#pragma unroll
            for (int nt = 0; nt < 8; nt++)
                acc[mt][nt] = __builtin_amdgcn_mfma_f32_16x16x32_bf16(bb[nt], aa[mt], acc[mt][nt], 0, 0, 0);
    }

#pragma unroll
    for (int mt = 0; mt < 2; mt++) {
        int r = rowBase + mt * 16 + l15;
        if (r < N) {
#pragma unroll
            for (int nt = 0; nt < 8; nt++) {
                int c0 = nt * 16 + quad * 4;
                ushort4 o;
                o.x = f2bf(acc[mt][nt][0]);
                o.y = f2bf(acc[mt][nt][1]);
                o.z = f2bf(acc[mt][nt][2]);
                o.w = f2bf(acc[mt][nt][3]);
                *(ushort4*)(xproj + (size_t)r * DIM + c0) = o;
            }
        }
    }
}

// One wave per node. Lane holds 2 dims (packed bf16 pair in xproj). fp32 accumulate,
// fp32 output (float2 per lane, coalesced 512B per row).
__global__ __launch_bounds__(256) void aggregate(const unsigned short* __restrict__ xproj,
                                                 const unsigned* __restrict__ row_start,
                                                 const unsigned* __restrict__ deg,
                                                 const float* __restrict__ dis,
                                                 const int* __restrict__ col_src,
                                                 float* __restrict__ out, int N) {
    int wid = (int)((blockIdx.x * 256 + threadIdx.x) >> 6);
    if (wid >= N) return;
    int lane = threadIdx.x & 63;
    const unsigned* xp = (const unsigned*)xproj;   // 2 bf16 per unsigned, 64 per row

    float di = dis[wid];
    unsigned sv = xp[(size_t)wid * 64 + lane];
    float sw = di * di;                             // self-loop weight
    float ax = bfu_lo(sv) * sw;
    float ay = bfu_hi(sv) * sw;

    unsigned rs = row_start[wid];
    unsigned cnt = deg[wid];
    for (unsigned e = 0; e < cnt; e++) {
        int s = col_src[rs + e];
        float w = dis[s] * di;
        unsigned v = xp[(size_t)s * 64 + lane];
        ax += bfu_lo(v) * w;
        ay += bfu_hi(v) * w;
    }
    float2 o; o.x = ax; o.y = ay;                  // cols 2*lane, 2*lane+1
    ((float2*)out)[(size_t)wid * 64 + lane] = o;
}

extern "C" void kernel_launch(void* const* d_in, const int* in_sizes, int n_in,
                              void* d_out, int out_size, void* d_ws, size_t ws_size,
                              hipStream_t stream) {
    const int N = in_sizes[0] / DIM;
    const int E = in_sizes[1] / 2;
    const float* x = (const float*)d_in[0];                     // fp32 [N][128]
    const void* ei = d_in[1];                                   // int32 or int64 [2][E]
    const float* W = (const float*)d_in[2];                     // fp32 [128][128]
    float* out = (float*)d_out;                                 // fp32 [N][128]

    char* wsp = (char*)d_ws;
    size_t off = 0;
    auto alloc = [&](size_t b) { void* p = wsp + off; off += (b + 255) & ~(size_t)255; return p; };
    int*      flags      = (int*)alloc(256);
    unsigned* deg        = (unsigned*)alloc((size_t)N * 4);
    unsigned* row_start  = (unsigned*)alloc((size_t)N * 4);
    unsigned* cursor     = (unsigned*)alloc((size_t)N * 4);
    unsigned* blockSums  = (unsigned*)alloc(4096);
    float*    dis        = (float*)alloc((size_t)N * 4);
    int*      col_src    = (int*)alloc((size_t)E * 4);
    unsigned short* Wt   = (unsigned short*)alloc((size_t)DIM * DIM * 2);
    unsigned short* xprj = (unsigned short*)alloc((size_t)N * DIM * 2);

    int nb = (N + 255) / 256;
    detect<<<1, 256, 0, stream>>>((const unsigned*)ei, flags);
    zero_u32<<<nb, 256, 0, stream>>>(deg, N);
    count_deg<<<(E + 255) / 256, 256, 0, stream>>>(ei, deg, flags, E);
    scan1<<<nb, 256, 0, stream>>>(deg, row_start, blockSums, N);
    scan2<<<1, 512, 0, stream>>>(blockSums, nb);
    finalize_csr<<<nb, 256, 0, stream>>>(deg, row_start, cursor, dis, blockSums, N);
    fill_csr<<<(E + 255) / 256, 256, 0, stream>>>(ei, cursor, col_src, flags, E);
    transposeW<<<(DIM * DIM + 255) / 256, 256, 0, stream>>>(W, Wt);
    gemm_xw<<<(N + 127) / 128, 256, 0, stream>>>(x, Wt, xprj, N);
    aggregate<<<(N + 3) / 4, 256, 0, stream>>>(xprj, row_start, deg, dis, col_src, out, N);
}

// Round 4
// 375.556 us; speedup vs baseline: 1.2710x; 1.2710x over previous
//
#include <hip/hip_runtime.h>
#include <hip/hip_bf16.h>

#define DIM 128

typedef __attribute__((ext_vector_type(8))) short bf16x8;
typedef __attribute__((ext_vector_type(4))) float f32x4;

__device__ __forceinline__ float bfu_lo(unsigned u) { return __uint_as_float(u << 16); }
__device__ __forceinline__ float bfu_hi(unsigned u) { return __uint_as_float(u & 0xffff0000u); }
__device__ __forceinline__ unsigned short f2bf(float f) {
    unsigned u = __float_as_uint(f);
    u += 0x7fffu + ((u >> 16) & 1u);   // round-to-nearest-even
    return (unsigned short)(u >> 16);
}

// Zero deg everywhere; block 0 additionally sniffs edge width.
// flags[0]=1 iff edge_index is int64 (odd 32-bit words -- high halves -- all zero).
__global__ void init_detect(const unsigned* ei_w, int* flags, unsigned* deg, int N) {
    int i = blockIdx.x * 256 + threadIdx.x;
    if (i < N) deg[i] = 0u;
    if (blockIdx.x == 0) {
        __shared__ unsigned s_or[256];
        int t = threadIdx.x;
        unsigned o = 0;
        for (int k = t; k < 4096; k += 256) o |= ei_w[2 * k + 1];
        s_or[t] = o;
        __syncthreads();
        for (int s = 128; s > 0; s >>= 1) {
            if (t < s) s_or[t] |= s_or[t + s];
            __syncthreads();
        }
        if (t == 0) flags[0] = (s_or[0] == 0u) ? 1 : 0;
    }
}

__device__ __forceinline__ int edge_at(const void* ei, int idx64, long long pos) {
    return idx64 ? (int)((const long long*)ei)[pos] : ((const int*)ei)[pos];
}

// deg[d] = number of incoming edges at d (self-loop added later as +1)
__global__ void count_deg(const void* ei, unsigned* deg, const int* flags, int E) {
    int e = blockIdx.x * 256 + threadIdx.x;
    int idx64 = flags[0];
    if (e < E) {
        int d = edge_at(ei, idx64, (long long)E + e);
        atomicAdd(&deg[d], 1u);
    }
}

// per-block exclusive scan of deg -> row_start (partial), block totals -> blockSums
__global__ void scan1(const unsigned* deg, unsigned* row_start, unsigned* blockSums, int N) {
    __shared__ unsigned wsum[4];
    int t = threadIdx.x;
    int i = blockIdx.x * 256 + t;
    unsigned v = (i < N) ? deg[i] : 0u;
    unsigned s = v;
    int lane = t & 63;
#pragma unroll
    for (int off = 1; off < 64; off <<= 1) {
        unsigned u = __shfl_up(s, off, 64);
        if (lane >= off) s += u;
    }
    int w = t >> 6;
    if (lane == 63) wsum[w] = s;
    __syncthreads();
    unsigned woff = 0;
    for (int j = 0; j < w; j++) woff += wsum[j];
    unsigned excl = woff + s - v;
    if (i < N) row_start[i] = excl;
    if (t == 255) blockSums[blockIdx.x] = woff + s;
}

// single-block exclusive scan of blockSums (nb <= 512)
__global__ void scan2(unsigned* blockSums, int nb) {
    __shared__ unsigned wsum[8];
    int t = threadIdx.x;
    unsigned v = (t < nb) ? blockSums[t] : 0u;
    unsigned s = v;
    int lane = t & 63;
#pragma unroll
    for (int off = 1; off < 64; off <<= 1) {
        unsigned u = __shfl_up(s, off, 64);
        if (lane >= off) s += u;
    }
    int w = t >> 6;
    if (lane == 63) wsum[w] = s;
    __syncthreads();
    unsigned woff = 0;
    for (int j = 0; j < w; j++) woff += wsum[j];
    if (t < nb) blockSums[t] = woff + s - v;
}

__global__ void finalize_csr(const unsigned* deg, unsigned* row_start, unsigned* cursor,
                             float* dis, const unsigned* blockSums, int N) {
    int i = blockIdx.x * 256 + threadIdx.x;
    if (i < N) {
        unsigned rs = row_start[i] + blockSums[i >> 8];
        row_start[i] = rs;
        cursor[i] = rs;
        dis[i] = rsqrtf((float)deg[i] + 1.0f);  // +1 self-loop
    }
}

__global__ void fill_csr(const void* ei, unsigned* cursor, int* col_src, const int* flags, int E) {
    int e = blockIdx.x * 256 + threadIdx.x;
    int idx64 = flags[0];
    if (e < E) {
        int s = edge_at(ei, idx64, e);
        int d = edge_at(ei, idx64, (long long)E + e);
        unsigned pos = atomicAdd(&cursor[d], 1u);
        col_src[pos] = s;
    }
}

// Wt[n][k] = bf16(W[k][n]); W is fp32 [128][128]
__global__ void transposeW(const float* W, unsigned short* Wt) {
    int idx = blockIdx.x * 256 + threadIdx.x;   // 0..DIM*DIM-1
    if (idx < DIM * DIM) {
        int n = idx >> 7, k = idx & 127;
        Wt[idx] = f2bf(W[k * DIM + n]);
    }
}

// xps = dis[row] * (x @ W), bf16 MFMA, fp32 x in / packed-bf16 out (pre-scaled).
// Block = 256 thr = 4 waves, 128 rows/block.
// Operand swap: mfma(Wfrag, Xfrag, acc) -> lane holds out[row=rowBase+l15][col=quad*4+reg]
__global__ __launch_bounds__(256) void gemm_xw(const float* __restrict__ x,
                                               const unsigned short* __restrict__ wt,
                                               const float* __restrict__ dis,
                                               unsigned short* __restrict__ xps, int N) {
    int tid = threadIdx.x;
    int wv = tid >> 6, lane = tid & 63;
    int l15 = lane & 15, quad = lane >> 4;
    int rowBase = blockIdx.x * 128 + wv * 32;

    f32x4 acc[2][8];
#pragma unroll
    for (int mt = 0; mt < 2; mt++)
#pragma unroll
        for (int nt = 0; nt < 8; nt++)
            acc[mt][nt] = (f32x4){0.f, 0.f, 0.f, 0.f};

#pragma unroll
    for (int k0 = 0; k0 < DIM; k0 += 32) {
        bf16x8 aa[2], bb[8];
#pragma unroll
        for (int mt = 0; mt < 2; mt++) {
            int r = rowBase + mt * 16 + l15;
            if (r > N - 1) r = N - 1;           // clamp; garbage rows never stored
            const float* xf = x + (size_t)r * DIM + k0 + quad * 8;
            float4 u0 = ((const float4*)xf)[0];
            float4 u1 = ((const float4*)xf)[1];
            bf16x8 a;
            a[0] = (short)f2bf(u0.x); a[1] = (short)f2bf(u0.y);
            a[2] = (short)f2bf(u0.z); a[3] = (short)f2bf(u0.w);
            a[4] = (short)f2bf(u1.x); a[5] = (short)f2bf(u1.y);
            a[6] = (short)f2bf(u1.z); a[7] = (short)f2bf(u1.w);
            aa[mt] = a;
        }
#pragma unroll
        for (int nt = 0; nt < 8; nt++)
            bb[nt] = *(const bf16x8*)(wt + (size_t)(nt * 16 + l15) * DIM + k0 + quad * 8);
#pragma unroll
        for (int mt = 0; mt < 2; mt++)
#pragma unroll
            for (int nt = 0; nt < 8; nt++)
                acc[mt][nt] = __builtin_amdgcn_mfma_f32_16x16x32_bf16(bb[nt], aa[mt], acc[mt][nt], 0, 0, 0);
    }

#pragma unroll
    for (int mt = 0; mt < 2; mt++) {
        int r = rowBase + mt * 16 + l15;
        if (r < N) {
            float sc = dis[r];                  // pre-scale by source-side dis
#pragma unroll
            for (int nt = 0; nt < 8; nt++) {
                int c0 = nt * 16 + quad * 4;
                ushort4 o;
                o.x = f2bf(acc[mt][nt][0] * sc);
                o.y = f2bf(acc[mt][nt][1] * sc);
                o.z = f2bf(acc[mt][nt][2] * sc);
                o.w = f2bf(acc[mt][nt][3] * sc);
                *(ushort4*)(xps + (size_t)r * DIM + c0) = o;
            }
        }
    }
}

// One wave per node. 16 lanes per edge row (uint4 = 16B = 8 bf16 each), 4 edge
// slots per wave, inner loop unrolled x2 (8 slots / iter) for MLP. Indices are
// prefetched 64-at-a-time (one coalesced load) and shfl-broadcast. Self-loop is
// virtual slot `cnt` (index wid). out[d] = dis[d] * sum(xps).
__global__ __launch_bounds__(256) void aggregate(const unsigned short* __restrict__ xps,
                                                 const unsigned* __restrict__ row_start,
                                                 const unsigned* __restrict__ deg,
                                                 const float* __restrict__ dis,
                                                 const int* __restrict__ col_src,
                                                 float* __restrict__ out, int N) {
    int wid = (int)((blockIdx.x * 256 + threadIdx.x) >> 6);
    if (wid >= N) return;
    int lane = threadIdx.x & 63;
    int grp = lane >> 4, lin = lane & 15;
    const uint4* xp4 = (const uint4*)xps;       // row = 16 x uint4

    float acc[8];
#pragma unroll
    for (int j = 0; j < 8; j++) acc[j] = 0.f;

    unsigned rs = row_start[wid];
    unsigned cnt = deg[wid];
    unsigned tot = cnt + 1;                      // + virtual self slot

    for (unsigned base = 0; base < tot; base += 64) {
        unsigned slot = base + (unsigned)lane;
        int idx = (slot < cnt) ? col_src[rs + slot] : wid;   // invalid/self -> wid (safe)
        unsigned rem = tot - base; if (rem > 64) rem = 64;
        for (unsigned q = 0; q * 8 < rem; q++) {
            unsigned sl0 = q * 8 + (unsigned)grp;
            unsigned sl1 = sl0 + 4;
            int s0 = __shfl(idx, (int)sl0, 64);
            int s1 = __shfl(idx, (int)sl1, 64);
            float m0 = (sl0 < rem) ? 1.f : 0.f;
            float m1 = (sl1 < rem) ? 1.f : 0.f;
            uint4 v0 = xp4[(size_t)s0 * 16 + lin];
            uint4 v1 = xp4[(size_t)s1 * 16 + lin];
            acc[0] = fmaf(bfu_lo(v0.x), m0, acc[0]);
            acc[1] = fmaf(bfu_hi(v0.x), m0, acc[1]);
            acc[2] = fmaf(bfu_lo(v0.y), m0, acc[2]);
            acc[3] = fmaf(bfu_hi(v0.y), m0, acc[3]);
            acc[4] = fmaf(bfu_lo(v0.z), m0, acc[4]);
            acc[5] = fmaf(bfu_hi(v0.z), m0, acc[5]);
            acc[6] = fmaf(bfu_lo(v0.w), m0, acc[6]);
            acc[7] = fmaf(bfu_hi(v0.w), m0, acc[7]);
            acc[0] = fmaf(bfu_lo(v1.x), m1, acc[0]);
            acc[1] = fmaf(bfu_hi(v1.x), m1, acc[1]);
            acc[2] = fmaf(bfu_lo(v1.y), m1, acc[2]);
            acc[3] = fmaf(bfu_hi(v1.y), m1, acc[3]);
            acc[4] = fmaf(bfu_lo(v1.z), m1, acc[4]);
            acc[5] = fmaf(bfu_hi(v1.z), m1, acc[5]);
            acc[6] = fmaf(bfu_lo(v1.w), m1, acc[6]);
            acc[7] = fmaf(bfu_hi(v1.w), m1, acc[7]);
        }
    }

    // reduce across the 4 groups (lanes differing in bits 4 and 5)
#pragma unroll
    for (int j = 0; j < 8; j++) {
        acc[j] += __shfl_xor(acc[j], 16, 64);
        acc[j] += __shfl_xor(acc[j], 32, 64);
    }

    float di = dis[wid];
    if (grp < 2) {                               // 32 lanes store the 512B row
        int jb = (grp & 1) * 4;
        float4 o;
        o.x = acc[jb + 0] * di;
        o.y = acc[jb + 1] * di;
        o.z = acc[jb + 2] * di;
        o.w = acc[jb + 3] * di;
        *(float4*)(out + (size_t)wid * DIM + lin * 8 + jb) = o;
    }
}

extern "C" void kernel_launch(void* const* d_in, const int* in_sizes, int n_in,
                              void* d_out, int out_size, void* d_ws, size_t ws_size,
                              hipStream_t stream) {
    const int N = in_sizes[0] / DIM;
    const int E = in_sizes[1] / 2;
    const float* x = (const float*)d_in[0];                     // fp32 [N][128]
    const void* ei = d_in[1];                                   // int32 or int64 [2][E]
    const float* W = (const float*)d_in[2];                     // fp32 [128][128]
    float* out = (float*)d_out;                                 // fp32 [N][128]

    char* wsp = (char*)d_ws;
    size_t off = 0;
    auto alloc = [&](size_t b) { void* p = wsp + off; off += (b + 255) & ~(size_t)255; return p; };
    int*      flags      = (int*)alloc(256);
    unsigned* deg        = (unsigned*)alloc((size_t)N * 4);
    unsigned* row_start  = (unsigned*)alloc((size_t)N * 4);
    unsigned* cursor     = (unsigned*)alloc((size_t)N * 4);
    unsigned* blockSums  = (unsigned*)alloc(4096);
    float*    dis        = (float*)alloc((size_t)N * 4);
    int*      col_src    = (int*)alloc((size_t)E * 4);
    unsigned short* Wt   = (unsigned short*)alloc((size_t)DIM * DIM * 2);
    unsigned short* xps  = (unsigned short*)alloc((size_t)N * DIM * 2);

    int nb = (N + 255) / 256;
    init_detect<<<nb, 256, 0, stream>>>((const unsigned*)ei, flags, deg, N);
    count_deg<<<(E + 255) / 256, 256, 0, stream>>>(ei, deg, flags, E);
    scan1<<<nb, 256, 0, stream>>>(deg, row_start, blockSums, N);
    scan2<<<1, 512, 0, stream>>>(blockSums, nb);
    finalize_csr<<<nb, 256, 0, stream>>>(deg, row_start, cursor, dis, blockSums, N);
    fill_csr<<<(E + 255) / 256, 256, 0, stream>>>(ei, cursor, col_src, flags, E);
    transposeW<<<(DIM * DIM + 255) / 256, 256, 0, stream>>>(W, Wt);
    gemm_xw<<<(N + 127) / 128, 256, 0, stream>>>(x, Wt, dis, xps, N);
    aggregate<<<(N + 3) / 4, 256, 0, stream>>>(xps, row_start, deg, dis, col_src, out, N);
}

// Round 5
// 331.063 us; speedup vs baseline: 1.4418x; 1.1344x over previous
//
#include <hip/hip_runtime.h>
#include <hip/hip_bf16.h>

#define DIM 128

typedef __attribute__((ext_vector_type(8))) short bf16x8;
typedef __attribute__((ext_vector_type(4))) float f32x4;

__device__ __forceinline__ float bfu_lo(unsigned u) { return __uint_as_float(u << 16); }
__device__ __forceinline__ float bfu_hi(unsigned u) { return __uint_as_float(u & 0xffff0000u); }
__device__ __forceinline__ unsigned short f2bf(float f) {
    unsigned u = __float_as_uint(f);
    u += 0x7fffu + ((u >> 16) & 1u);   // round-to-nearest-even
    return (unsigned short)(u >> 16);
}

// Zero deg everywhere; block 0 additionally sniffs edge width.
// flags[0]=1 iff edge_index is int64 (odd 32-bit words -- high halves -- all zero).
__global__ void init_detect(const unsigned* ei_w, int* flags, unsigned* deg, int N) {
    int i = blockIdx.x * 256 + threadIdx.x;
    if (i < N) deg[i] = 0u;
    if (blockIdx.x == 0) {
        __shared__ unsigned s_or[256];
        int t = threadIdx.x;
        unsigned o = 0;
        for (int k = t; k < 4096; k += 256) o |= ei_w[2 * k + 1];
        s_or[t] = o;
        __syncthreads();
        for (int s = 128; s > 0; s >>= 1) {
            if (t < s) s_or[t] |= s_or[t + s];
            __syncthreads();
        }
        if (t == 0) flags[0] = (s_or[0] == 0u) ? 1 : 0;
    }
}

__device__ __forceinline__ int edge_at(const void* ei, int idx64, long long pos) {
    return idx64 ? (int)((const long long*)ei)[pos] : ((const int*)ei)[pos];
}

// deg[d] = number of incoming edges at d (self-loop added later as +1)
__global__ void count_deg(const void* ei, unsigned* deg, const int* flags, int E) {
    int e = blockIdx.x * 256 + threadIdx.x;
    int idx64 = flags[0];
    if (e < E) {
        int d = edge_at(ei, idx64, (long long)E + e);
        atomicAdd(&deg[d], 1u);
    }
}

// per-block exclusive scan of deg -> row_start (partial), block totals -> blockSums
__global__ void scan1(const unsigned* deg, unsigned* row_start, unsigned* blockSums, int N) {
    __shared__ unsigned wsum[4];
    int t = threadIdx.x;
    int i = blockIdx.x * 256 + t;
    unsigned v = (i < N) ? deg[i] : 0u;
    unsigned s = v;
    int lane = t & 63;
#pragma unroll
    for (int off = 1; off < 64; off <<= 1) {
        unsigned u = __shfl_up(s, off, 64);
        if (lane >= off) s += u;
    }
    int w = t >> 6;
    if (lane == 63) wsum[w] = s;
    __syncthreads();
    unsigned woff = 0;
    for (int j = 0; j < w; j++) woff += wsum[j];
    unsigned excl = woff + s - v;
    if (i < N) row_start[i] = excl;
    if (t == 255) blockSums[blockIdx.x] = woff + s;
}

// single-block exclusive scan of blockSums (nb <= 512)
__global__ void scan2(unsigned* blockSums, int nb) {
    __shared__ unsigned wsum[8];
    int t = threadIdx.x;
    unsigned v = (t < nb) ? blockSums[t] : 0u;
    unsigned s = v;
    int lane = t & 63;
#pragma unroll
    for (int off = 1; off < 64; off <<= 1) {
        unsigned u = __shfl_up(s, off, 64);
        if (lane >= off) s += u;
    }
    int w = t >> 6;
    if (lane == 63) wsum[w] = s;
    __syncthreads();
    unsigned woff = 0;
    for (int j = 0; j < w; j++) woff += wsum[j];
    if (t < nb) blockSums[t] = woff + s - v;
}

__global__ void finalize_csr(const unsigned* deg, unsigned* row_start, unsigned* cursor,
                             float* dis, const unsigned* blockSums, int N) {
    int i = blockIdx.x * 256 + threadIdx.x;
    if (i < N) {
        unsigned rs = row_start[i] + blockSums[i >> 8];
        row_start[i] = rs;
        cursor[i] = rs;
        dis[i] = rsqrtf((float)deg[i] + 1.0f);  // +1 self-loop
    }
}

// Destination-striped CSR fill. blockIdx = chunk*8 + stripe, so stripe ==
// blockIdx % 8 == (heuristically) the XCD id under round-robin dispatch.
// Stripe k's col_src segment (~0.8 MB) then stays write-combined in XCD k's
// L2 -> full-line writebacks instead of 64B-per-dword churn.
__global__ void fill_csr_striped(const void* ei, unsigned* cursor, int* col_src,
                                 const int* flags, int E, int N) {
    int stripe = blockIdx.x & 7;
    int chunk  = blockIdx.x >> 3;
    int idx64  = flags[0];
    unsigned lo = (unsigned)(((unsigned long long)N * (unsigned)stripe) >> 3);
    unsigned hi = (unsigned)(((unsigned long long)N * (unsigned)(stripe + 1)) >> 3);
    int base = chunk * 1024 + threadIdx.x;
#pragma unroll
    for (int j = 0; j < 4; j++) {
        int e = base + j * 256;
        if (e < E) {
            int d = edge_at(ei, idx64, (long long)E + e);
            if ((unsigned)d >= lo && (unsigned)d < hi) {
                int s = edge_at(ei, idx64, e);
                unsigned pos = atomicAdd(&cursor[d], 1u);
                col_src[pos] = s;
            }
        }
    }
}

// Wt[n][k] = bf16(W[k][n]); W is fp32 [128][128]
__global__ void transposeW(const float* W, unsigned short* Wt) {
    int idx = blockIdx.x * 256 + threadIdx.x;   // 0..DIM*DIM-1
    if (idx < DIM * DIM) {
        int n = idx >> 7, k = idx & 127;
        Wt[idx] = f2bf(W[k * DIM + n]);
    }
}

// xps = dis[row] * (x @ W), bf16 MFMA, fp32 x in / packed-bf16 out (pre-scaled).
// Block = 256 thr = 4 waves, 128 rows/block.
// Operand swap: mfma(Wfrag, Xfrag, acc) -> lane holds out[row=rowBase+l15][col=quad*4+reg]
__global__ __launch_bounds__(256) void gemm_xw(const float* __restrict__ x,
                                               const unsigned short* __restrict__ wt,
                                               const float* __restrict__ dis,
                                               unsigned short* __restrict__ xps, int N) {
    int tid = threadIdx.x;
    int wv = tid >> 6, lane = tid & 63;
    int l15 = lane & 15, quad = lane >> 4;
    int rowBase = blockIdx.x * 128 + wv * 32;

    f32x4 acc[2][8];
#pragma unroll
    for (int mt = 0; mt < 2; mt++)
#pragma unroll
        for (int nt = 0; nt < 8; nt++)
            acc[mt][nt] = (f32x4){0.f, 0.f, 0.f, 0.f};

#pragma unroll
    for (int k0 = 0; k0 < DIM; k0 += 32) {
        bf16x8 aa[2], bb[8];
#pragma unroll
        for (int mt = 0; mt < 2; mt++) {
            int r = rowBase + mt * 16 + l15;
            if (r > N - 1) r = N - 1;           // clamp; garbage rows never stored
            const float* xf = x + (size_t)r * DIM + k0 + quad * 8;
            float4 u0 = ((const float4*)xf)[0];
            float4 u1 = ((const float4*)xf)[1];
            bf16x8 a;
            a[0] = (short)f2bf(u0.x); a[1] = (short)f2bf(u0.y);
            a[2] = (short)f2bf(u0.z); a[3] = (short)f2bf(u0.w);
            a[4] = (short)f2bf(u1.x); a[5] = (short)f2bf(u1.y);
            a[6] = (short)f2bf(u1.z); a[7] = (short)f2bf(u1.w);
            aa[mt] = a;
        }
#pragma unroll
        for (int nt = 0; nt < 8; nt++)
            bb[nt] = *(const bf16x8*)(wt + (size_t)(nt * 16 + l15) * DIM + k0 + quad * 8);
#pragma unroll
        for (int mt = 0; mt < 2; mt++)
#pragma unroll
            for (int nt = 0; nt < 8; nt++)
                acc[mt][nt] = __builtin_amdgcn_mfma_f32_16x16x32_bf16(bb[nt], aa[mt], acc[mt][nt], 0, 0, 0);
    }

#pragma unroll
    for (int mt = 0; mt < 2; mt++) {
        int r = rowBase + mt * 16 + l15;
        if (r < N) {
            float sc = dis[r];                  // pre-scale by source-side dis
#pragma unroll
            for (int nt = 0; nt < 8; nt++) {
                int c0 = nt * 16 + quad * 4;
                ushort4 o;
                o.x = f2bf(acc[mt][nt][0] * sc);
                o.y = f2bf(acc[mt][nt][1] * sc);
                o.z = f2bf(acc[mt][nt][2] * sc);
                o.w = f2bf(acc[mt][nt][3] * sc);
                *(ushort4*)(xps + (size_t)r * DIM + c0) = o;
            }
        }
    }
}

// One wave per node. 16 lanes per edge row (uint4 = 16B = 8 bf16 each), 4 edge
// slots per wave, inner loop unrolled x2 (8 slots / iter) for MLP. Indices are
// prefetched 64-at-a-time (one coalesced load) and shfl-broadcast. Self-loop is
// virtual slot `cnt` (index wid). out[d] = dis[d] * sum(xps).
__global__ __launch_bounds__(256) void aggregate(const unsigned short* __restrict__ xps,
                                                 const unsigned* __restrict__ row_start,
                                                 const unsigned* __restrict__ deg,
                                                 const float* __restrict__ dis,
                                                 const int* __restrict__ col_src,
                                                 float* __restrict__ out, int N) {
    int wid = (int)((blockIdx.x * 256 + threadIdx.x) >> 6);
    if (wid >= N) return;
    int lane = threadIdx.x & 63;
    int grp = lane >> 4, lin = lane & 15;
    const uint4* xp4 = (const uint4*)xps;       // row = 16 x uint4

    float acc[8];
#pragma unroll
    for (int j = 0; j < 8; j++) acc[j] = 0.f;

    unsigned rs = row_start[wid];
    unsigned cnt = deg[wid];
    unsigned tot = cnt + 1;                      // + virtual self slot

    for (unsigned base = 0; base < tot; base += 64) {
        unsigned slot = base + (unsigned)lane;
        int idx = (slot < cnt) ? col_src[rs + slot] : wid;   // invalid/self -> wid (safe)
        unsigned rem = tot - base; if (rem > 64) rem = 64;
        for (unsigned q = 0; q * 8 < rem; q++) {
            unsigned sl0 = q * 8 + (unsigned)grp;
            unsigned sl1 = sl0 + 4;
            int s0 = __shfl(idx, (int)sl0, 64);
            int s1 = __shfl(idx, (int)sl1, 64);
            float m0 = (sl0 < rem) ? 1.f : 0.f;
            float m1 = (sl1 < rem) ? 1.f : 0.f;
            uint4 v0 = xp4[(size_t)s0 * 16 + lin];
            uint4 v1 = xp4[(size_t)s1 * 16 + lin];
            acc[0] = fmaf(bfu_lo(v0.x), m0, acc[0]);
            acc[1] = fmaf(bfu_hi(v0.x), m0, acc[1]);
            acc[2] = fmaf(bfu_lo(v0.y), m0, acc[2]);
            acc[3] = fmaf(bfu_hi(v0.y), m0, acc[3]);
            acc[4] = fmaf(bfu_lo(v0.z), m0, acc[4]);
            acc[5] = fmaf(bfu_hi(v0.z), m0, acc[5]);
            acc[6] = fmaf(bfu_lo(v0.w), m0, acc[6]);
            acc[7] = fmaf(bfu_hi(v0.w), m0, acc[7]);
            acc[0] = fmaf(bfu_lo(v1.x), m1, acc[0]);
            acc[1] = fmaf(bfu_hi(v1.x), m1, acc[1]);
            acc[2] = fmaf(bfu_lo(v1.y), m1, acc[2]);
            acc[3] = fmaf(bfu_hi(v1.y), m1, acc[3]);
            acc[4] = fmaf(bfu_lo(v1.z), m1, acc[4]);
            acc[5] = fmaf(bfu_hi(v1.z), m1, acc[5]);
            acc[6] = fmaf(bfu_lo(v1.w), m1, acc[6]);
            acc[7] = fmaf(bfu_hi(v1.w), m1, acc[7]);
        }
    }

    // reduce across the 4 groups (lanes differing in bits 4 and 5)
#pragma unroll
    for (int j = 0; j < 8; j++) {
        acc[j] += __shfl_xor(acc[j], 16, 64);
        acc[j] += __shfl_xor(acc[j], 32, 64);
    }

    float di = dis[wid];
    if (grp < 2) {                               // 32 lanes store the 512B row
        int jb = (grp & 1) * 4;
        float4 o;
        o.x = acc[jb + 0] * di;
        o.y = acc[jb + 1] * di;
        o.z = acc[jb + 2] * di;
        o.w = acc[jb + 3] * di;
        *(float4*)(out + (size_t)wid * DIM + lin * 8 + jb) = o;
    }
}

extern "C" void kernel_launch(void* const* d_in, const int* in_sizes, int n_in,
                              void* d_out, int out_size, void* d_ws, size_t ws_size,
                              hipStream_t stream) {
    const int N = in_sizes[0] / DIM;
    const int E = in_sizes[1] / 2;
    const float* x = (const float*)d_in[0];                     // fp32 [N][128]
    const void* ei = d_in[1];                                   // int32 or int64 [2][E]
    const float* W = (const float*)d_in[2];                     // fp32 [128][128]
    float* out = (float*)d_out;                                 // fp32 [N][128]

    char* wsp = (char*)d_ws;
    size_t off = 0;
    auto alloc = [&](size_t b) { void* p = wsp + off; off += (b + 255) & ~(size_t)255; return p; };
    int*      flags      = (int*)alloc(256);
    unsigned* deg        = (unsigned*)alloc((size_t)N * 4);
    unsigned* row_start  = (unsigned*)alloc((size_t)N * 4);
    unsigned* cursor     = (unsigned*)alloc((size_t)N * 4);
    unsigned* blockSums  = (unsigned*)alloc(4096);
    float*    dis        = (float*)alloc((size_t)N * 4);
    int*      col_src    = (int*)alloc((size_t)E * 4);
    unsigned short* Wt   = (unsigned short*)alloc((size_t)DIM * DIM * 2);
    unsigned short* xps  = (unsigned short*)alloc((size_t)N * DIM * 2);

    int nb = (N + 255) / 256;
    init_detect<<<nb, 256, 0, stream>>>((const unsigned*)ei, flags, deg, N);
    count_deg<<<(E + 255) / 256, 256, 0, stream>>>(ei, deg, flags, E);
    scan1<<<nb, 256, 0, stream>>>(deg, row_start, blockSums, N);
    scan2<<<1, 512, 0, stream>>>(blockSums, nb);
    finalize_csr<<<nb, 256, 0, stream>>>(deg, row_start, cursor, dis, blockSums, N);
    int nchunks = (E + 1023) / 1024;
    fill_csr_striped<<<nchunks * 8, 256, 0, stream>>>(ei, cursor, col_src, flags, E, N);
    transposeW<<<(DIM * DIM + 255) / 256, 256, 0, stream>>>(W, Wt);
    gemm_xw<<<(N + 127) / 128, 256, 0, stream>>>(x, Wt, dis, xps, N);
    aggregate<<<(N + 3) / 4, 256, 0, stream>>>(xps, row_start, deg, dis, col_src, out, N);
}